// Round 1
// baseline (203.139 us; speedup 1.0000x reference)
//
#include <hip/hip_runtime.h>
#include <math.h>

// Problem constants (from setup_inputs): b=2, h=4, n_tot=585, d=128, n=512, k=8
// Levels: L0 = rows [0,512), L1 = [512,576), L2 = [576,584), L3 = [584,585)
#define D 128
#define NTOT 585
#define SCALE 0.08838834764831845f  // 1/sqrt(128)

__device__ __forceinline__ float wave_reduce_sum(float v) {
#pragma unroll
    for (int off = 32; off > 0; off >>= 1) v += __shfl_xor(v, off, 64);
    return v;
}
__device__ __forceinline__ float wave_reduce_max(float v) {
#pragma unroll
    for (int off = 32; off > 0; off >>= 1) v = fmaxf(v, __shfl_xor(v, off, 64));
    return v;
}

// One softmax-attention over exactly 8 selector entries.
// Kb: K base for this (b,h) slice (K is never updated).
// kidx[s]: row index for the key; vrow[s]: pointer to the 128-float V row
// (may be global original-V, global updated-out, or LDS) chosen per the
// update schedule. Each lane owns dims {2*lane, 2*lane+1}.
__device__ __forceinline__ void attend8(const float* __restrict__ Kb, float2 q, int lane,
                                        const int* kidx, const float* const* vrow,
                                        float& acc0, float& acc1) {
    float logits[8];
#pragma unroll
    for (int s = 0; s < 8; ++s) {
        const float2 kv = *(const float2*)(Kb + (size_t)kidx[s] * D + lane * 2);
        logits[s] = wave_reduce_sum(q.x * kv.x + q.y * kv.y) * SCALE;
    }
    float m = logits[0];
#pragma unroll
    for (int s = 1; s < 8; ++s) m = fmaxf(m, logits[s]);
    float w[8];
    float sum = 0.f;
#pragma unroll
    for (int s = 0; s < 8; ++s) { w[s] = __expf(logits[s] - m); sum += w[s]; }
    const float inv = 1.f / sum;
#pragma unroll
    for (int s = 0; s < 8; ++s) {
        const float2 vv = *(const float2*)(vrow[s] + lane * 2);
        const float ws = w[s] * inv;
        acc0 += ws * vv.x;
        acc1 += ws * vv.y;
    }
}

// ---------------- Kernel A: level 0 (512 queries x 8 bh slices) --------------
// One wave per query. Everything reads ORIGINAL Q/K/V. Writes Out rows [0,512).
__global__ __launch_bounds__(256) void level0_kernel(const float* __restrict__ Q,
                                                     const float* __restrict__ K,
                                                     const float* __restrict__ V,
                                                     float* __restrict__ Out) {
    const int gwave = (blockIdx.x * blockDim.x + threadIdx.x) >> 6;
    const int lane = threadIdx.x & 63;
    const int i = gwave & 511;   // query row within level 0
    const int bh = gwave >> 9;   // 0..7
    const float* Qb = Q + (size_t)bh * NTOT * D;
    const float* Kb = K + (size_t)bh * NTOT * D;
    const float* Vb = V + (size_t)bh * NTOT * D;
    float* Ob = Out + (size_t)bh * NTOT * D;

    const float2 q = *(const float2*)(Qb + (size_t)i * D + lane * 2);
    float acc0 = 0.f, acc1 = 0.f;

    // ---- sib: 8 keys, idx = (g*8+s <= i) ? g*8+s : 0, all original V ----
    {
        const int g = i >> 3;
        int kidx[8];
        const float* vrow[8];
#pragma unroll
        for (int s = 0; s < 8; ++s) {
            const int r = g * 8 + s;
            const int idx = (r <= i) ? r : 0;
            kidx[s] = idx;
            vrow[s] = Vb + (size_t)idx * D;
        }
        attend8(Kb, q, lane, kidx, vrow, acc0, acc1);
    }

    // ---- anc: 64 keys, idx_j = (8*(j+1) <= i) ? 512+j : 0, original V ----
    {
        float mylogit = 0.f;
#pragma unroll
        for (int t = 0; t < 64; ++t) {
            const int idx = (8 * (t + 1) <= i) ? (512 + t) : 0;  // wave-uniform
            const float2 kv = *(const float2*)(Kb + (size_t)idx * D + lane * 2);
            const float logit = wave_reduce_sum(q.x * kv.x + q.y * kv.y) * SCALE;
            if (lane == t) mylogit = logit;   // lane t keeps logit t
        }
        const float m = wave_reduce_max(mylogit);
        const float e = __expf(mylogit - m);
        const float s = wave_reduce_sum(e);
        const float w = e / s;
#pragma unroll
        for (int t = 0; t < 64; ++t) {
            const float wt = __shfl(w, t, 64);
            const int idx = (8 * (t + 1) <= i) ? (512 + t) : 0;  // wave-uniform
            const float2 vv = *(const float2*)(Vb + (size_t)idx * D + lane * 2);
            acc0 += wt * vv.x;
            acc1 += wt * vv.y;
        }
    }

    const float2 o = make_float2(acc0 * (1.f / 3.f), acc1 * (1.f / 3.f));
    *(float2*)(Ob + (size_t)i * D + lane * 2) = o;
}

// ------------- Kernel B: levels 1..3, one block per (b,h) slice --------------
// Updated rows for this slice live in LDS between levels:
//   LDS rows [0,64)  = global rows 512+r (level-1 outputs)
//   LDS rows [64,72) = global rows 576+r (level-2 outputs)
//   LDS row  72      = updated V[0] (level-0 output, read from Out)
__global__ __launch_bounds__(256) void levels123_kernel(const float* __restrict__ Q,
                                                        const float* __restrict__ K,
                                                        const float* __restrict__ V,
                                                        float* __restrict__ Out) {
    __shared__ float Vnew[73 * D];
    const int bh = blockIdx.x;
    const int tid = threadIdx.x;
    const int lane = tid & 63;
    const int wid = tid >> 6;  // 0..3
    const float* Qb = Q + (size_t)bh * NTOT * D;
    const float* Kb = K + (size_t)bh * NTOT * D;
    const float* Vb = V + (size_t)bh * NTOT * D;
    float* Ob = Out + (size_t)bh * NTOT * D;

    // Stage updated V[0] (kernel A output) into LDS.
    for (int t = tid; t < D; t += blockDim.x) Vnew[72 * D + t] = Ob[t];
    __syncthreads();
    const float* Vzero = &Vnew[72 * D];

    // ---------------- level 1: 64 queries (global rows 512+i) ---------------
    for (int i = wid; i < 64; i += 4) {
        const float2 q = *(const float2*)(Qb + (size_t)(512 + i) * D + lane * 2);
        float acc0 = 0.f, acc1 = 0.f;
        // sib: r = g*8+s; r<=i -> row 512+r ORIGINAL V; else row 0 UPDATED
        {
            const int g = i >> 3;
            int kidx[8];
            const float* vrow[8];
#pragma unroll
            for (int s = 0; s < 8; ++s) {
                const int r = g * 8 + s;
                if (r <= i) { kidx[s] = 512 + r; vrow[s] = Vb + (size_t)(512 + r) * D; }
                else        { kidx[s] = 0;       vrow[s] = Vzero; }
            }
            attend8(Kb, q, lane, kidx, vrow, acc0, acc1);
        }
        // anc: (j+1)*8 <= i -> row 576+j ORIGINAL V; else row 0 UPDATED
        {
            int kidx[8];
            const float* vrow[8];
#pragma unroll
            for (int j = 0; j < 8; ++j) {
                if ((j + 1) * 8 <= i) { kidx[j] = 576 + j; vrow[j] = Vb + (size_t)(576 + j) * D; }
                else                  { kidx[j] = 0;       vrow[j] = Vzero; }
            }
            attend8(Kb, q, lane, kidx, vrow, acc0, acc1);
        }
        // chi: only c=0 passes -> row 8i UPDATED (kernel A out); c>=1 -> row 0 UPDATED
        {
            int kidx[8];
            const float* vrow[8];
            kidx[0] = 8 * i;
            vrow[0] = Ob + (size_t)(8 * i) * D;
#pragma unroll
            for (int c = 1; c < 8; ++c) { kidx[c] = 0; vrow[c] = Vzero; }
            attend8(Kb, q, lane, kidx, vrow, acc0, acc1);
        }
        const float2 o = make_float2(acc0 * (1.f / 3.f), acc1 * (1.f / 3.f));
        *(float2*)(&Vnew[i * D + lane * 2]) = o;
        *(float2*)(Ob + (size_t)(512 + i) * D + lane * 2) = o;
    }
    __syncthreads();

    // ---------------- level 2: 8 queries (global rows 576+i) ----------------
    for (int i = wid; i < 8; i += 4) {
        const float2 q = *(const float2*)(Qb + (size_t)(576 + i) * D + lane * 2);
        float acc0 = 0.f, acc1 = 0.f;
        // sib: s<=i -> row 576+s ORIGINAL V; else row 0 UPDATED
        {
            int kidx[8];
            const float* vrow[8];
#pragma unroll
            for (int s = 0; s < 8; ++s) {
                if (s <= i) { kidx[s] = 576 + s; vrow[s] = Vb + (size_t)(576 + s) * D; }
                else        { kidx[s] = 0;       vrow[s] = Vzero; }
            }
            attend8(Kb, q, lane, kidx, vrow, acc0, acc1);
        }
        // anc: single entry, always masked -> softmax weight 1 on updated V[0]
        {
            const float2 vz = *(const float2*)(Vzero + lane * 2);
            acc0 += vz.x;
            acc1 += vz.y;
        }
        // chi: c=0 -> row 512+8i UPDATED (LDS level-1 row 8i); c>=1 -> row 0 UPDATED
        {
            int kidx[8];
            const float* vrow[8];
            kidx[0] = 512 + 8 * i;
            vrow[0] = &Vnew[(8 * i) * D];
#pragma unroll
            for (int c = 1; c < 8; ++c) { kidx[c] = 0; vrow[c] = Vzero; }
            attend8(Kb, q, lane, kidx, vrow, acc0, acc1);
        }
        const float2 o = make_float2(acc0 * (1.f / 3.f), acc1 * (1.f / 3.f));
        *(float2*)(&Vnew[(64 + i) * D + lane * 2]) = o;
        *(float2*)(Ob + (size_t)(576 + i) * D + lane * 2) = o;
    }
    __syncthreads();

    // ---------------- level 3: 1 query (global row 584) ----------------------
    if (wid == 0) {
        const float2 q = *(const float2*)(Qb + (size_t)584 * D + lane * 2);
        float acc0 = 0.f, acc1 = 0.f;
        // sib: all 8 entries are row 584 (ORIGINAL V) -> softmax sums to V[584]
        {
            int kidx[8];
            const float* vrow[8];
#pragma unroll
            for (int s = 0; s < 8; ++s) { kidx[s] = 584; vrow[s] = Vb + (size_t)584 * D; }
            attend8(Kb, q, lane, kidx, vrow, acc0, acc1);
        }
        // chi: c=0 -> row 576 UPDATED (LDS level-2 row 0); c>=1 -> row 0 UPDATED
        {
            int kidx[8];
            const float* vrow[8];
            kidx[0] = 576;
            vrow[0] = &Vnew[64 * D];
#pragma unroll
            for (int c = 1; c < 8; ++c) { kidx[c] = 0; vrow[c] = Vzero; }
            attend8(Kb, q, lane, kidx, vrow, acc0, acc1);
        }
        const float2 o = make_float2(acc0 * (1.f / 3.f), acc1 * (1.f / 3.f));
        *(float2*)(Ob + (size_t)584 * D + lane * 2) = o;
    }
}

extern "C" void kernel_launch(void* const* d_in, const int* in_sizes, int n_in,
                              void* d_out, int out_size, void* d_ws, size_t ws_size,
                              hipStream_t stream) {
    const float* Q = (const float*)d_in[0];
    const float* K = (const float*)d_in[1];
    const float* V = (const float*)d_in[2];
    float* Out = (float*)d_out;
    // 8 bh-slices x 512 level-0 queries = 4096 waves; 4 waves/block -> 1024 blocks
    hipLaunchKernelGGL(level0_kernel, dim3(1024), dim3(256), 0, stream, Q, K, V, Out);
    // levels 1..3: one block per (b,h) slice, LDS-carried updates between levels
    hipLaunchKernelGGL(levels123_kernel, dim3(8), dim3(256), 0, stream, Q, K, V, Out);
}

// Round 2
// 90.758 us; speedup vs baseline: 2.2382x; 2.2382x over previous
//
#include <hip/hip_runtime.h>
#include <math.h>

// Problem constants: b=2, h=4, n_tot=585, d=128, n=512, k=8
// Levels: L0 rows [0,512), L1 [512,576), L2 [576,584), L3 {584}
// Lane layout: s = lane>>3 (key slot 0..7), c = lane&7 (dim chunk of 16)
#define D 128
#define NTOT 585
#define SCALE 0.08838834764831845f  // 1/sqrt(128)
#define THIRD 0.33333333333333333f

__device__ __forceinline__ float rsum_c(float v) {  // sum over c (lanes stride 1,2,4)
    v += __shfl_xor(v, 1, 64);
    v += __shfl_xor(v, 2, 64);
    v += __shfl_xor(v, 4, 64);
    return v;
}
__device__ __forceinline__ float rsum_s(float v) {  // sum over s (lanes stride 8,16,32)
    v += __shfl_xor(v, 8, 64);
    v += __shfl_xor(v, 16, 64);
    v += __shfl_xor(v, 32, 64);
    return v;
}
__device__ __forceinline__ float rmax_s(float v) {  // max over s
    v = fmaxf(v, __shfl_xor(v, 8, 64));
    v = fmaxf(v, __shfl_xor(v, 16, 64));
    v = fmaxf(v, __shfl_xor(v, 32, 64));
    return v;
}

// 16-dim partial dot: this lane's q chunk (4 float4) vs row[16c..16c+16)
__device__ __forceinline__ float dot16(const float4 q[4], const float* __restrict__ row, int c) {
    const float4* k = (const float4*)(row + (c << 4));
    float4 k0 = k[0], k1 = k[1], k2 = k[2], k3 = k[3];
    float p0 = q[0].x * k0.x + q[0].y * k0.y + q[0].z * k0.z + q[0].w * k0.w;
    float p1 = q[1].x * k1.x + q[1].y * k1.y + q[1].z * k1.z + q[1].w * k1.w;
    float p2 = q[2].x * k2.x + q[2].y * k2.y + q[2].z * k2.z + q[2].w * k2.w;
    float p3 = q[3].x * k3.x + q[3].y * k3.y + q[3].z * k3.z + q[3].w * k3.w;
    return (p0 + p1) + (p2 + p3);
}

// acc[u] += w * row[16c + 4u .. +4)
__device__ __forceinline__ void vacc(float w, const float* __restrict__ row, int c, float4 acc[4]) {
    const float4* v = (const float4*)(row + (c << 4));
#pragma unroll
    for (int u = 0; u < 4; ++u) {
        float4 t = v[u];
        acc[u].x += w * t.x; acc[u].y += w * t.y; acc[u].z += w * t.z; acc[u].w += w * t.w;
    }
}

// One 8-entry softmax attend; lane-group s owns entry s (krow/vrow are per-lane).
// Accumulates partials (to be butterflied over s once per query).
__device__ __forceinline__ void attend(const float4 q[4], const float* __restrict__ krow,
                                       const float* __restrict__ vrow, int c, float4 acc[4]) {
    float lg = rsum_c(dot16(q, krow, c)) * SCALE;
    float m = rmax_s(lg);
    float e = __expf(lg - m);
    float z = rsum_s(e);
    vacc(e / z, vrow, c, acc);
}

__device__ __forceinline__ void loadq(const float* __restrict__ qrow, int c, float4 q[4]) {
    const float4* qp = (const float4*)(qrow + (c << 4));
#pragma unroll
    for (int u = 0; u < 4; ++u) q[u] = qp[u];
}

__device__ __forceinline__ void butterfly_acc(float4 acc[4]) {
#pragma unroll
    for (int u = 0; u < 4; ++u) {
        acc[u].x = rsum_s(acc[u].x);
        acc[u].y = rsum_s(acc[u].y);
        acc[u].z = rsum_s(acc[u].z);
        acc[u].w = rsum_s(acc[u].w);
    }
}

// ---------------- Level 0: 4096 queries, one wave each -----------------------
__global__ __launch_bounds__(256) void level0_kernel(const float* __restrict__ Q,
                                                     const float* __restrict__ K,
                                                     const float* __restrict__ V,
                                                     float* __restrict__ Out) {
    const int gwave = (blockIdx.x * 256 + threadIdx.x) >> 6;
    const int lane = threadIdx.x & 63;
    const int s = lane >> 3, c = lane & 7;
    const int i = gwave & 511;
    const int bh = gwave >> 9;
    const float* Qb = Q + (size_t)bh * NTOT * D;
    const float* Kb = K + (size_t)bh * NTOT * D;
    const float* Vb = V + (size_t)bh * NTOT * D;
    float* Ob = Out + (size_t)bh * NTOT * D;

    float4 q4[4];
    loadq(Qb + (size_t)i * D, c, q4);
    float4 acc[4] = {{0,0,0,0},{0,0,0,0},{0,0,0,0},{0,0,0,0}};

    // sib: entry s -> row r = (i&~7)+s if r<=i else 0; K and V both ORIGINAL
    {
        const int r = (i & ~7) + s;
        const int idx = (r <= i) ? r : 0;
        attend(q4, Kb + (size_t)idx * D, Vb + (size_t)idx * D, c, acc);
    }

    // anc: 64 entries in 8 rounds; round r, lane-group s handles j = 8r+s
    {
        float lg[8];
        int idx[8];
#pragma unroll
        for (int r = 0; r < 8; ++r) {
            const int j = 8 * r + s;
            idx[r] = (8 * (j + 1) <= i) ? (512 + j) : 0;
            lg[r] = rsum_c(dot16(q4, Kb + (size_t)idx[r] * D, c)) * SCALE;
        }
        float m = lg[0];
#pragma unroll
        for (int r = 1; r < 8; ++r) m = fmaxf(m, lg[r]);
        m = rmax_s(m);
        float z = 0.f;
#pragma unroll
        for (int r = 0; r < 8; ++r) { lg[r] = __expf(lg[r] - m); z += lg[r]; }
        z = rsum_s(z);
        const float inv = 1.f / z;
#pragma unroll
        for (int r = 0; r < 8; ++r) vacc(lg[r] * inv, Vb + (size_t)idx[r] * D, c, acc);
    }

    butterfly_acc(acc);
    if (s == 0) {
        float4* orow = (float4*)(Ob + (size_t)i * D + (c << 4));
#pragma unroll
        for (int u = 0; u < 4; ++u) {
            orow[u] = make_float4(acc[u].x * THIRD, acc[u].y * THIRD,
                                  acc[u].z * THIRD, acc[u].w * THIRD);
        }
    }
}

// ---------------- Level 1: 512 queries, one wave each ------------------------
// Reads: original Q/K/V, plus UPDATED rows from Out (level-0 outputs + row 0).
__global__ __launch_bounds__(256) void level1_kernel(const float* __restrict__ Q,
                                                     const float* __restrict__ K,
                                                     const float* __restrict__ V,
                                                     float* __restrict__ Out) {
    const int gwave = (blockIdx.x * 256 + threadIdx.x) >> 6;
    const int lane = threadIdx.x & 63;
    const int s = lane >> 3, c = lane & 7;
    const int i = gwave & 63;
    const int bh = gwave >> 6;
    const float* Qb = Q + (size_t)bh * NTOT * D;
    const float* Kb = K + (size_t)bh * NTOT * D;
    const float* Vb = V + (size_t)bh * NTOT * D;
    float* Ob = Out + (size_t)bh * NTOT * D;

    float4 q4[4];
    loadq(Qb + (size_t)(512 + i) * D, c, q4);
    float4 acc[4] = {{0,0,0,0},{0,0,0,0},{0,0,0,0},{0,0,0,0}};

    // sib: r<=i -> row 512+r (K; V ORIGINAL); masked -> row 0 (V UPDATED = Out)
    {
        const int r = (i & ~7) + s;
        const bool pass = (r <= i);
        const float* krow = Kb + (size_t)(pass ? 512 + r : 0) * D;
        const float* vrow = pass ? (Vb + (size_t)(512 + r) * D) : Ob;
        attend(q4, krow, vrow, c, acc);
    }
    // anc: (s+1)*8<=i -> row 576+s ORIGINAL V; masked -> row 0 UPDATED
    {
        const bool pass = (8 * (s + 1) <= i);
        const float* krow = Kb + (size_t)(pass ? 576 + s : 0) * D;
        const float* vrow = pass ? (Vb + (size_t)(576 + s) * D) : Ob;
        attend(q4, krow, vrow, c, acc);
    }
    // chi: s==0 -> row 8i (UPDATED level-0, from Out); s>=1 masked -> row 0 UPDATED
    {
        const int idx = (s == 0) ? 8 * i : 0;
        attend(q4, Kb + (size_t)idx * D, Ob + (size_t)idx * D, c, acc);
    }

    butterfly_acc(acc);
    if (s == 0) {
        float4* orow = (float4*)(Ob + (size_t)(512 + i) * D + (c << 4));
#pragma unroll
        for (int u = 0; u < 4; ++u) {
            orow[u] = make_float4(acc[u].x * THIRD, acc[u].y * THIRD,
                                  acc[u].z * THIRD, acc[u].w * THIRD);
        }
    }
}

// ---------------- Levels 2+3: 8 blocks (one per bh), 8 waves each ------------
// Wave w computes level-2 query i=w (row 576+w). Wave 0 then computes level 3
// (row 584) using its own level-2 i=0 output kept in registers — no sync.
__global__ __launch_bounds__(512) void levels23_kernel(const float* __restrict__ Q,
                                                       const float* __restrict__ K,
                                                       const float* __restrict__ V,
                                                       float* __restrict__ Out) {
    const int bh = blockIdx.x;
    const int wave = threadIdx.x >> 6;
    const int lane = threadIdx.x & 63;
    const int s = lane >> 3, c = lane & 7;
    const float* Qb = Q + (size_t)bh * NTOT * D;
    const float* Kb = K + (size_t)bh * NTOT * D;
    const float* Vb = V + (size_t)bh * NTOT * D;
    float* Ob = Out + (size_t)bh * NTOT * D;

    const int i = wave;  // level-2 query index 0..7
    float4 q4[4];
    loadq(Qb + (size_t)(576 + i) * D, c, q4);
    float4 acc[4] = {{0,0,0,0},{0,0,0,0},{0,0,0,0},{0,0,0,0}};

    // sib: s<=i -> row 576+s ORIGINAL V; masked -> row 0 UPDATED (Out)
    {
        const bool pass = (s <= i);
        const float* krow = Kb + (size_t)(pass ? 576 + s : 0) * D;
        const float* vrow = pass ? (Vb + (size_t)(576 + s) * D) : Ob;
        attend(q4, krow, vrow, c, acc);
    }
    // chi: s==0 -> row 512+8i UPDATED (Out, level-1); masked -> row 0 UPDATED
    {
        const int idx = (s == 0) ? (512 + 8 * i) : 0;
        attend(q4, Kb + (size_t)idx * D, Ob + (size_t)idx * D, c, acc);
    }

    butterfly_acc(acc);
    // anc: single always-masked entry -> softmax weight exactly 1 on UPDATED row 0.
    // Whole-row weight-1 term: add AFTER the butterfly (once, per-lane c-dims).
    float4 o23[4];
    {
        const float4* r0 = (const float4*)(Ob + (c << 4));
#pragma unroll
        for (int u = 0; u < 4; ++u) {
            float4 z = r0[u];
            o23[u] = make_float4((acc[u].x + z.x) * THIRD, (acc[u].y + z.y) * THIRD,
                                 (acc[u].z + z.z) * THIRD, (acc[u].w + z.w) * THIRD);
        }
    }
    if (s == 0) {
        float4* orow = (float4*)(Ob + (size_t)(576 + i) * D + (c << 4));
#pragma unroll
        for (int u = 0; u < 4; ++u) orow[u] = o23[u];
    }

    // ---------------- level 3 (wave 0 only): row 584 -------------------------
    if (wave == 0) {
        // o23 (all lanes) == updated row 576 chunk for this lane's c — exactly
        // what chi's s==0 entry needs.
        float4 q5[4];
        loadq(Qb + (size_t)584 * D, c, q5);
        // chi logits: s==0 -> K row 576; masked -> K row 0
        const float* krow = Kb + (size_t)((s == 0) ? 576 : 0) * D;
        float lg = rsum_c(dot16(q5, krow, c)) * SCALE;
        float m = rmax_s(lg);
        float e = __expf(lg - m);
        float z = rsum_s(e);
        const float w = e / z;
        // V: s==0 -> updated row 576 (registers); masked -> updated row 0 (Out)
        const float4* r0 = (const float4*)(Ob + (c << 4));
        float4 acc3[4];
#pragma unroll
        for (int u = 0; u < 4; ++u) {
            float4 vv = r0[u];
            if (s == 0) vv = o23[u];
            acc3[u] = make_float4(w * vv.x, w * vv.y, w * vv.z, w * vv.w);
        }
        butterfly_acc(acc3);
        // sib: 8 identical entries on row 584 -> weights exactly 1/8 each ->
        // contributes exactly ORIGINAL V[584]. Whole-row term: add post-butterfly.
        if (s == 0) {
            const float4* v584 = (const float4*)(Vb + (size_t)584 * D + (c << 4));
            float4* orow = (float4*)(Ob + (size_t)584 * D + (c << 4));
#pragma unroll
            for (int u = 0; u < 4; ++u) {
                float4 b = v584[u];
                orow[u] = make_float4((acc3[u].x + b.x) * THIRD, (acc3[u].y + b.y) * THIRD,
                                      (acc3[u].z + b.z) * THIRD, (acc3[u].w + b.w) * THIRD);
            }
        }
    }
}

extern "C" void kernel_launch(void* const* d_in, const int* in_sizes, int n_in,
                              void* d_out, int out_size, void* d_ws, size_t ws_size,
                              hipStream_t stream) {
    const float* Q = (const float*)d_in[0];
    const float* K = (const float*)d_in[1];
    const float* V = (const float*)d_in[2];
    float* Out = (float*)d_out;
    // L0: 4096 waves (8 bh x 512 queries), 4 waves/block
    hipLaunchKernelGGL(level0_kernel, dim3(1024), dim3(256), 0, stream, Q, K, V, Out);
    // L1: 512 waves (8 bh x 64 queries), depends on L0 output in Out
    hipLaunchKernelGGL(level1_kernel, dim3(128), dim3(256), 0, stream, Q, K, V, Out);
    // L2+L3: 8 blocks x 8 waves; level 3 chains inside wave 0 (no barrier)
    hipLaunchKernelGGL(levels23_kernel, dim3(8), dim3(512), 0, stream, Q, K, V, Out);
}